// Round 7
// baseline (1112.722 us; speedup 1.0000x reference)
//
#include <hip/hip_runtime.h>
#include <math.h>

#define BB 16
#define NP 196
#define HH 4
#define KVD 960
#define KP 224    // K=196 padded to multiple of 32 for clean global_load_lds staging

typedef __attribute__((ext_vector_type(8))) short s8v;
typedef __attribute__((ext_vector_type(8))) unsigned short u8v;
typedef __attribute__((ext_vector_type(4))) unsigned short u4v;
typedef __attribute__((ext_vector_type(4))) float f4v;

static inline int divup(int a, int b){ return (a+b-1)/b; }
static inline int imin(int a, int b){ return a < b ? a : b; }

__device__ __forceinline__ unsigned short bf16r(float x){
    unsigned int u = __float_as_uint(x);
    u += 0x7fffu + ((u >> 16) & 1u);       // round-to-nearest-even
    return (unsigned short)(u >> 16);
}
__device__ __forceinline__ float bf16f(unsigned short h){
    return __uint_as_float(((unsigned int)h) << 16);
}

// async global->LDS, 16B per lane; LDS dest = uniform base + lane*16
__device__ __forceinline__ void gload16(const unsigned short* g, unsigned short* l){
    __builtin_amdgcn_global_load_lds(
        (const __attribute__((address_space(1))) void*)g,
        (__attribute__((address_space(3))) void*)l, 16, 0, 0);
}

// ---------------------------------------------------------------------------
// one-shot decompose of all 15 fp32 inputs -> bf16 (hi,lo) pairs.
// blockIdx.y = input index; grid-stride over that input's float4 count.
// ---------------------------------------------------------------------------
struct DecTable {
    const float* src[15];
    unsigned short* dh[15];
    unsigned short* dl[15];
    long n4[15];
};

__global__ __launch_bounds__(256)
void decomp_all(DecTable T)
{
    int seg = blockIdx.y;
    const float* x = T.src[seg];
    unsigned short* hi = T.dh[seg];
    unsigned short* lo = T.dl[seg];
    long n4 = T.n4[seg];
    for (long i = (long)blockIdx.x * 256 + threadIdx.x; i < n4; i += (long)gridDim.x * 256) {
        float4 v = ((const float4*)x)[i];
        float a[4] = {v.x, v.y, v.z, v.w};
        u4v h, l;
#pragma unroll
        for (int e = 0; e < 4; e++) {
            unsigned short hb = bf16r(a[e]);
            h[e] = hb;
            l[e] = bf16r(a[e] - bf16f(hb));
        }
        *(u4v*)(hi + i * 4) = h;
        *(u4v*)(lo + i * 4) = l;
    }
}

// ---------------------------------------------------------------------------
// Split-bf16 NT GEMM via MFMA: C[M,Nn] = alpha * A[M,Kk] * B[Nn,Kk]^T
// (round-4 verified core: 37.9% MfmaUtil, 0 bank conflicts)
// STATS=1: per-block partial sum/sumsq -> part[z*64 + slot*2], slot=bx+8*by
// ---------------------------------------------------------------------------
template<int OSPLIT, int STATS>
__global__ __launch_bounds__(256)
void gemm_split(const unsigned short* __restrict__ Ah, const unsigned short* __restrict__ Al,
                const unsigned short* __restrict__ Bh, const unsigned short* __restrict__ Bl,
                float* __restrict__ Cf, unsigned short* __restrict__ Ch,
                unsigned short* __restrict__ Cl, double* __restrict__ part,
                int M, int Nn, int Kk, int ldA, int ldB, int ldC,
                long sAb, long sAh_, long sBb, long sBh_, long sCb, long sCh_,
                int Hdiv, float alpha)
{
    __shared__ u8v AsV[128 * 8];
    __shared__ u8v BsV[128 * 8];
    unsigned short* As = (unsigned short*)AsV;
    unsigned short* Bs = (unsigned short*)BsV;

    int z  = blockIdx.z;
    int bb = z / Hdiv, hz = z - bb * Hdiv;
    const unsigned short* gah = Ah + (long)bb * sAb + (long)hz * sAh_;
    const unsigned short* gal = Al + (long)bb * sAb + (long)hz * sAh_;
    const unsigned short* gbh = Bh + (long)bb * sBb + (long)hz * sBh_;
    const unsigned short* gbl = Bl + (long)bb * sBb + (long)hz * sBh_;
    long coff = (long)bb * sCb + (long)hz * sCh_;

    int t = threadIdx.x;
    int m0 = blockIdx.y * 128, n0 = blockIdx.x * 128;
    int wave = t >> 6, lane = t & 63;
    int wm = wave >> 1, wn = wave & 1;
    int lr = lane & 15, lk = lane >> 4;

    int ls   = (lane & 7) ^ (lane >> 3);
    int comp = ls >> 2;
    int chnk = ls & 3;
    const unsigned short* gA = comp ? gal : gah;
    const unsigned short* gB = comp ? gbl : gbh;
    const unsigned short* aptr[4];
    const unsigned short* bptr[4];
#pragma unroll
    for (int j = 0; j < 4; j++) {
        int ra = m0 + wave * 32 + j * 8 + (lane >> 3);
        ra = (ra < M) ? ra : (M - 1);
        aptr[j] = gA + (long)ra * ldA + chnk * 8;
        int rb = n0 + wave * 32 + j * 8 + (lane >> 3);
        rb = (rb < Nn) ? rb : (Nn - 1);
        bptr[j] = gB + (long)rb * ldB + chnk * 8;
    }

    f4v acc[4][4];
#pragma unroll
    for (int i = 0; i < 4; i++)
#pragma unroll
        for (int j = 0; j < 4; j++) acc[i][j] = (f4v){0.f, 0.f, 0.f, 0.f};

    int nkt = Kk >> 5;
    for (int kt = 0; kt < nkt; ++kt) {
        int k0 = kt << 5;
#pragma unroll
        for (int j = 0; j < 4; j++) {
            gload16(aptr[j] + k0, As + (wave * 4 + j) * 512);
            gload16(bptr[j] + k0, Bs + (wave * 4 + j) * 512);
        }
        __syncthreads();

        s8v afh[4], afl[4], bfh[4], bfl[4];
#pragma unroll
        for (int i = 0; i < 4; i++) {
            int rw = wm * 64 + i * 16 + lr;
            afh[i] = *(const s8v*)&As[rw * 64 + ((lk ^ (rw & 7)) << 3)];
            afl[i] = *(const s8v*)&As[rw * 64 + (((lk + 4) ^ (rw & 7)) << 3)];
            int cw = wn * 64 + i * 16 + lr;
            bfh[i] = *(const s8v*)&Bs[cw * 64 + ((lk ^ (cw & 7)) << 3)];
            bfl[i] = *(const s8v*)&Bs[cw * 64 + (((lk + 4) ^ (cw & 7)) << 3)];
        }
#pragma unroll
        for (int i = 0; i < 4; i++)
#pragma unroll
            for (int j = 0; j < 4; j++) {
                acc[i][j] = __builtin_amdgcn_mfma_f32_16x16x32_bf16(afh[i], bfh[j], acc[i][j], 0, 0, 0);
                acc[i][j] = __builtin_amdgcn_mfma_f32_16x16x32_bf16(afl[i], bfh[j], acc[i][j], 0, 0, 0);
                acc[i][j] = __builtin_amdgcn_mfma_f32_16x16x32_bf16(afh[i], bfl[j], acc[i][j], 0, 0, 0);
            }
        __syncthreads();
    }

    float s1 = 0.f, s2 = 0.f;
#pragma unroll
    for (int i = 0; i < 4; i++)
#pragma unroll
        for (int j = 0; j < 4; j++)
#pragma unroll
            for (int r = 0; r < 4; r++) {
                int gr = m0 + wm * 64 + i * 16 + lk * 4 + r;
                int gc = n0 + wn * 64 + j * 16 + lr;
                if (gr < M) {
                    if (gc < Nn) {
                        float v = acc[i][j][r] * alpha;
                        if (STATS) { s1 += v; s2 += v * v; }
                        if (OSPLIT) {
                            unsigned short hb = bf16r(v);
                            Ch[coff + (long)gr * ldC + gc] = hb;
                            Cl[coff + (long)gr * ldC + gc] = bf16r(v - bf16f(hb));
                        } else {
                            Cf[coff + (long)gr * ldC + gc] = v;
                        }
                    } else if (OSPLIT && gc < ldC) {
                        Ch[coff + (long)gr * ldC + gc] = 0;
                        Cl[coff + (long)gr * ldC + gc] = 0;
                    }
                }
            }

    if (STATS) {
        double* sh = (double*)AsV;
        sh[t] = (double)s1; sh[256 + t] = (double)s2;
        __syncthreads();
        for (int o = 128; o > 0; o >>= 1) {
            if (t < o) { sh[t] += sh[t + o]; sh[256 + t] += sh[256 + t + o]; }
            __syncthreads();
        }
        if (t == 0) {
            int slot = blockIdx.x + (int)gridDim.x * blockIdx.y;
            part[(long)z * 64 + slot * 2 + 0] = sh[0];
            part[(long)z * 64 + slot * 2 + 1] = sh[256];
        }
    }
}

// ---------------------------------------------------------------------------
// Fused softmax+PV: ctx[c,196] = softmax_kv((S-mu)*is) @ V^T, per map.
// Stats read from per-block slots (nslot pairs per map). V: [bh][196][960].
// ---------------------------------------------------------------------------
__global__ __launch_bounds__(256)
void pv_fused(const float* __restrict__ Sb, const unsigned short* __restrict__ Vh,
              const unsigned short* __restrict__ Vl, const double* __restrict__ part,
              float* __restrict__ Cb, int c, int m0, int nslot)
{
    __shared__ unsigned short As[64 * 64];    // P tile: 64 rows x 32kv (hi|lo), XOR-swizzled
    __shared__ unsigned short Bs[224 * 64];   // V tile: 224 cols x 32kv (hi|lo)
    __shared__ float Zlds[64];
    __shared__ float bc2[2];

    int z  = blockIdx.z;
    int gm = m0 + z;                 // group-local map
    int my0 = blockIdx.y * 64;

    int t = threadIdx.x;
    int wave = t >> 6, lane = t & 63;
    int wm = wave >> 1, wn = wave & 1;
    int lr = lane & 15, lk = lane >> 4;

    if (t == 0) {
        const double* pp = part + (long)gm * 64;
        double su = 0.0, sq = 0.0;
        for (int q = 0; q < nslot; q++) { su += pp[q * 2]; sq += pp[q * 2 + 1]; }
        float inv_e = 1.0f / (float)(c * KVD);
        float mean = (float)(su * (double)inv_e);
        float var  = (float)(sq * (double)inv_e) - mean * mean;
        float is   = rsqrtf(var + 1e-5f);
        bc2[0] = is; bc2[1] = -mean * is;
    }
    __syncthreads();
    float is = bc2[0], dd = bc2[1];

    // A (P) staging map: thread t -> row t>>2, 8-kv chunk t&3
    int arow = t >> 2, achk = t & 3;
    const float* sp = Sb + (size_t)z * c * KVD + (size_t)(my0 + arow) * KVD + achk * 8;
    unsigned short* awh = &As[arow * 64 + (( achk      ^ (arow & 7)) << 3)];
    unsigned short* awl = &As[arow * 64 + (((achk + 4) ^ (arow & 7)) << 3)];

    // B (V) staging: 7 gload16 per thread (224 rows x 128B)
    int ls   = (lane & 7) ^ (lane >> 3);
    int comp = ls >> 2, chnk = ls & 3;
    const unsigned short* vbase = (comp ? Vl : Vh) + (long)gm * (196L * KVD);
    const unsigned short* bptr[7];
    unsigned short* bdst[7];
#pragma unroll
    for (int q = 0; q < 7; q++) {
        int rlog = (wave * 7 + q) * 8 + (lane >> 3);
        int vrow = (rlog < NP) ? rlog : (NP - 1);
        bptr[q] = vbase + (long)vrow * KVD + chnk * 8;
        bdst[q] = &Bs[(wave * 7 + q) * 512];
    }

    f4v acc[2][7];
#pragma unroll
    for (int i = 0; i < 2; i++)
#pragma unroll
        for (int j = 0; j < 7; j++) acc[i][j] = (f4v){0.f, 0.f, 0.f, 0.f};
    float zp = 0.f;

    for (int kt = 0; kt < 30; ++kt) {
        int k0 = kt << 5;
#pragma unroll
        for (int q = 0; q < 7; q++) gload16(bptr[q] + k0, bdst[q]);

        float4 v0 = *(const float4*)(sp + k0);
        float4 v1 = *(const float4*)(sp + k0 + 4);
        float s[8] = {v0.x, v0.y, v0.z, v0.w, v1.x, v1.y, v1.z, v1.w};
        u8v hv, lv;
#pragma unroll
        for (int e = 0; e < 8; e++) {
            float p = __expf(fmaf(s[e], is, dd));
            zp += p;
            unsigned short hb = bf16r(p);
            hv[e] = hb;
            lv[e] = bf16r(p - bf16f(hb));
        }
        *(u8v*)awh = hv;
        *(u8v*)awl = lv;
        __syncthreads();

        s8v afh[2], afl[2], bfh[7], bfl[7];
#pragma unroll
        for (int i = 0; i < 2; i++) {
            int ar = wm * 32 + i * 16 + lr;
            afh[i] = *(const s8v*)&As[ar * 64 + ((lk ^ (ar & 7)) << 3)];
            afl[i] = *(const s8v*)&As[ar * 64 + (((lk + 4) ^ (ar & 7)) << 3)];
        }
#pragma unroll
        for (int j = 0; j < 7; j++) {
            int br = wn * 112 + j * 16 + lr;
            bfh[j] = *(const s8v*)&Bs[br * 64 + ((lk ^ (br & 7)) << 3)];
            bfl[j] = *(const s8v*)&Bs[br * 64 + (((lk + 4) ^ (br & 7)) << 3)];
        }
#pragma unroll
        for (int i = 0; i < 2; i++)
#pragma unroll
            for (int j = 0; j < 7; j++) {
                acc[i][j] = __builtin_amdgcn_mfma_f32_16x16x32_bf16(afh[i], bfh[j], acc[i][j], 0, 0, 0);
                acc[i][j] = __builtin_amdgcn_mfma_f32_16x16x32_bf16(afl[i], bfh[j], acc[i][j], 0, 0, 0);
                acc[i][j] = __builtin_amdgcn_mfma_f32_16x16x32_bf16(afh[i], bfl[j], acc[i][j], 0, 0, 0);
            }
        __syncthreads();
    }

    // per-row Z: 4 threads per row hold partials
    zp += __shfl_xor(zp, 1);
    zp += __shfl_xor(zp, 2);
    if ((t & 3) == 0) Zlds[arow] = zp;
    __syncthreads();

    float rz[2][4];
#pragma unroll
    for (int i = 0; i < 2; i++)
#pragma unroll
        for (int r = 0; r < 4; r++)
            rz[i][r] = 1.0f / Zlds[wm * 32 + i * 16 + lk * 4 + r];

    float* co = Cb + (size_t)gm * c * NP;
#pragma unroll
    for (int i = 0; i < 2; i++)
#pragma unroll
        for (int j = 0; j < 7; j++)
#pragma unroll
            for (int r = 0; r < 4; r++) {
                int grl = wm * 32 + i * 16 + lk * 4 + r;
                int gc  = wn * 112 + j * 16 + lr;
                if (gc < NP)
                    co[(size_t)(my0 + grl) * NP + gc] = acc[i][j][r] * rz[i][r];
            }
}

// ---------------------------------------------------------------------------
// head-mean + transpose: Mb[b,n,d] = 0.25 * sum_h Cb[(b*4+h), d, n], split out.
// ---------------------------------------------------------------------------
__global__ __launch_bounds__(256)
void mean_t_kernel(const float* __restrict__ Cb, unsigned short* __restrict__ Mh,
                   unsigned short* __restrict__ Ml, int c)
{
    int b  = blockIdx.z;
    int n0 = blockIdx.x * 32;
    int d0 = blockIdx.y * 32;
    __shared__ float tile[32][33];
    int tx = threadIdx.x & 31;
    int ty = threadIdx.x >> 5;
#pragma unroll
    for (int i = 0; i < 4; i++) {
        int d = d0 + ty + i * 8;
        int n = n0 + tx;
        float s = 0.f;
        if (n < NP) {
#pragma unroll
            for (int h = 0; h < HH; h++)
                s += Cb[(((long)(b * HH + h)) * c + d) * NP + n];
        }
        tile[ty + i * 8][tx] = 0.25f * s;
    }
    __syncthreads();
#pragma unroll
    for (int i = 0; i < 4; i++) {
        int n = n0 + ty + i * 8;
        int d = d0 + tx;
        if (n < NP) {
            float val = tile[tx][ty + i * 8];
            long idx = ((long)b * NP + n) * c + d;
            unsigned short hb = bf16r(val);
            Mh[idx] = hb;
            Ml[idx] = bf16r(val - bf16f(hb));
        }
    }
}

// ---------------------------------------------------------------------------
extern "C" void kernel_launch(void* const* d_in, const int* in_sizes, int n_in,
                              void* d_out, int out_size, void* d_ws, size_t ws_size,
                              hipStream_t stream)
{
    const float* embf[4] = {(const float*)d_in[0], (const float*)d_in[1],
                            (const float*)d_in[2], (const float*)d_in[3]};
    const float* emb_all = (const float*)d_in[4];
    const float* Wq[4]   = {(const float*)d_in[5], (const float*)d_in[6],
                            (const float*)d_in[7], (const float*)d_in[8]};
    const float* Wk = (const float*)d_in[9];
    const float* Wv = (const float*)d_in[10];
    const float* Wo[4]   = {(const float*)d_in[11], (const float*)d_in[12],
                            (const float*)d_in[13], (const float*)d_in[14]};
    float* out = (float*)d_out;

    const int Cc[4] = {64, 128, 256, 512};

    char* base = (char*)d_ws;
    size_t off = 0;
    auto carve = [&](size_t bytes) -> void* {
        void* p = base + off;
        off = (off + bytes + 255) & ~(size_t)255;
        return p;
    };

    const long NEA   = (long)BB * NP * KVD;
    const long NWKV  = (long)HH * KVD * KVD;
    const long SUMC2 = 64L*64 + 128L*128 + 256L*256 + 512L*512;

    // ---- fixed buffers: split weights + split emb_all + split emb_i + stats ----
    unsigned short* wkH = (unsigned short*)carve(NWKV * 2);
    unsigned short* wkL = (unsigned short*)carve(NWKV * 2);
    unsigned short* wvH = (unsigned short*)carve(NWKV * 2);
    unsigned short* wvL = (unsigned short*)carve(NWKV * 2);
    unsigned short* wqH = (unsigned short*)carve((long)HH * SUMC2 * 2);
    unsigned short* wqL = (unsigned short*)carve((long)HH * SUMC2 * 2);
    unsigned short* woH = (unsigned short*)carve(SUMC2 * 2);
    unsigned short* woL = (unsigned short*)carve(SUMC2 * 2);
    unsigned short* eaH = (unsigned short*)carve(NEA * 2);
    unsigned short* eaL = (unsigned short*)carve(NEA * 2);
    unsigned short* eiH = (unsigned short*)carve(NEA * 2);   // all 4 emb_i concatenated
    unsigned short* eiL = (unsigned short*)carve(NEA * 2);
    double* part = (double*)carve(64L * 64 * 8);             // [map][32 slots][2]

    // ---- adaptive batch grouping ----
    size_t fixed_off = off;
    auto group_bytes = [&](int gb) -> size_t {
        long nbh = (long)gb * HH;
        size_t s = 0;
        auto add = [&](size_t b){ s += (b + 255) & ~(size_t)255; };
        add(nbh * KVD * KP * 2); add(nbh * KVD * KP * 2);    // Kt hi/lo
        add(nbh * NP * KVD * 2); add(nbh * NP * KVD * 2);    // V hi/lo
        add(nbh * 512 * KP * 2); add(nbh * 512 * KP * 2);    // Qt hi/lo
        add(nbh * 512 * NP * 4);                             // Cb fp32
        add((long)gb * NP * 512 * 2); add((long)gb * NP * 512 * 2); // Mb hi/lo
        return s;
    };
    const size_t minchunk = (size_t)512 * KVD * 4 + (1 << 20);
    int GB = 16;
    while (GB > 1 && fixed_off + group_bytes(GB) + minchunk > ws_size) GB >>= 1;
    const long NBH = (long)GB * HH;

    unsigned short* KtH = (unsigned short*)carve(NBH * KVD * KP * 2);   // [bh][960][224]
    unsigned short* KtL = (unsigned short*)carve(NBH * KVD * KP * 2);
    unsigned short* VH  = (unsigned short*)carve(NBH * NP * KVD * 2);   // [bh][196][960]
    unsigned short* VL  = (unsigned short*)carve(NBH * NP * KVD * 2);
    unsigned short* QtH = (unsigned short*)carve(NBH * 512 * KP * 2);   // [b][4c][224]
    unsigned short* QtL = (unsigned short*)carve(NBH * 512 * KP * 2);
    float*  Cb          = (float*)carve(NBH * 512 * NP * 4);            // [bh][c][196]
    unsigned short* MbH = (unsigned short*)carve((long)GB * NP * 512 * 2);
    unsigned short* MbL = (unsigned short*)carve((long)GB * NP * 512 * 2);

    size_t savail = (ws_size > off) ? (ws_size - off) : 0;
    char* chunk = base + off;

    dim3 blk(256);
    const float alphaS = 1.0f / sqrtf((float)KVD);

    // ---- one-shot decompose of all inputs ----
    long eio[4], wqo[4], woo[4];
    { long eo = 0, qo = 0, oo = 0;
      for (int i = 0; i < 4; i++) {
          eio[i] = eo; eo += (long)BB * NP * Cc[i];
          wqo[i] = qo; qo += (long)HH * Cc[i] * Cc[i];
          woo[i] = oo; oo += (long)Cc[i] * Cc[i];
      } }
    {
        DecTable T;
        int k = 0;
        for (int i = 0; i < 4; i++) {   // emb1..4
            T.src[k] = embf[i]; T.dh[k] = eiH + eio[i]; T.dl[k] = eiL + eio[i];
            T.n4[k] = ((long)BB * NP * Cc[i]) / 4; k++;
        }
        T.src[k] = emb_all; T.dh[k] = eaH; T.dl[k] = eaL; T.n4[k] = NEA / 4; k++;
        for (int i = 0; i < 4; i++) {   // Wq1..4
            T.src[k] = Wq[i]; T.dh[k] = wqH + wqo[i]; T.dl[k] = wqL + wqo[i];
            T.n4[k] = ((long)HH * Cc[i] * Cc[i]) / 4; k++;
        }
        T.src[k] = Wk; T.dh[k] = wkH; T.dl[k] = wkL; T.n4[k] = NWKV / 4; k++;
        T.src[k] = Wv; T.dh[k] = wvH; T.dl[k] = wvL; T.n4[k] = NWKV / 4; k++;
        for (int i = 0; i < 4; i++) {   // Wo1..4
            T.src[k] = Wo[i]; T.dh[k] = woH + woo[i]; T.dl[k] = woL + woo[i];
            T.n4[k] = ((long)Cc[i] * Cc[i]) / 4; k++;
        }
        decomp_all<<<dim3(512, 15, 1), blk, 0, stream>>>(T);
    }

    long obase[4];
    { long o = 0; for (int i = 0; i < 4; i++) { obase[i] = o; o += (long)BB * NP * Cc[i]; } }

    // ---- batch-group passes ----
    for (int g0 = 0; g0 < BB; g0 += GB) {
        const unsigned short* eaHg = eaH + (long)g0 * NP * KVD;
        const unsigned short* eaLg = eaL + (long)g0 * NP * KVD;

        // Kt[bh][960][224] = Wk[h] @ emb_all[b]^T   (per-(b,h): measured-faster shape)
        gemm_split<1,0><<<dim3(2, 8, (int)NBH), blk, 0, stream>>>(
            wkH, wkL, eaHg, eaLg, nullptr, KtH, KtL, nullptr,
            KVD, NP, KVD, KVD, KVD, KP,
            0, (long)KVD * KVD, (long)NP * KVD, 0,
            (long)HH * KVD * KP, (long)KVD * KP, HH, 1.0f);

        // V[bh][196][960] = emb_all[b] @ Wv[h]^T
        gemm_split<1,0><<<dim3(8, 2, (int)NBH), blk, 0, stream>>>(
            eaHg, eaLg, wvH, wvL, nullptr, VH, VL, nullptr,
            NP, KVD, KVD, KVD, KVD, KVD,
            (long)NP * KVD, 0, 0, (long)KVD * KVD,
            (long)HH * NP * KVD, (long)NP * KVD, HH, 1.0f);

        for (int i = 0; i < 4; i++) {
            int c = Cc[i];

            // Qt[b][4c][224] = Wq_all_i @ emb_i[b]^T  (heads merged into M: full tiles)
            gemm_split<1,0><<<dim3(2, divup(HH * c, 128), GB), blk, 0, stream>>>(
                wqH + wqo[i], wqL + wqo[i],
                eiH + eio[i] + (long)g0 * NP * c, eiL + eio[i] + (long)g0 * NP * c,
                nullptr, QtH, QtL, nullptr,
                HH * c, NP, c, c, c, KP,
                0, 0, (long)NP * c, 0,
                (long)HH * c * KP, 0, 1, 1.0f);

            int nslot = 8 * divup(c, 128);

            size_t per = (size_t)c * KVD * 4;   // S fp32 per map
            int G = (savail >= per) ? (int)(savail / per) : 1;
            if (G > (int)NBH) G = (int)NBH;
            if (G < 1) G = 1;
            float* Sb = (float*)chunk;

            for (int m0 = 0; m0 < (int)NBH; m0 += G) {
                int g = imin(G, (int)NBH - m0);
                // S[c,960] = (Qt @ Kt^T)/sqrt(960); per-block stats slots
                gemm_split<0,1><<<dim3(8, divup(c, 128), g), blk, 0, stream>>>(
                    QtH + (size_t)m0 * c * KP, QtL + (size_t)m0 * c * KP,
                    KtH + (size_t)m0 * KVD * KP, KtL + (size_t)m0 * KVD * KP,
                    Sb, nullptr, nullptr, part + (size_t)m0 * 64,
                    c, KVD, KP, KP, KP, KVD,
                    (long)c * KP, 0, (long)KVD * KP, 0, (long)c * KVD, 0,
                    1, alphaS);
                // fused exp/Z/PV -> ctx fp32
                pv_fused<<<dim3(1, c / 64, g), blk, 0, stream>>>(
                    Sb, VH, VL, part, Cb, c, m0, nslot);
            }
            // head-mean + transpose -> split Mb[b_local,n,d]
            mean_t_kernel<<<dim3(divup(NP, 32), c / 32, GB), blk, 0, stream>>>(Cb, MbH, MbL, c);
            // O rows for this group = Mb @ Wo^T
            gemm_split<0,0><<<dim3(divup(c, 128), divup(GB * NP, 128), 1), blk, 0, stream>>>(
                MbH, MbL, woH + woo[i], woL + woo[i],
                out + obase[i] + (long)g0 * NP * c, nullptr, nullptr, nullptr,
                GB * NP, c, c, c, c, c,
                0, 0, 0, 0, 0, 0, 1, 1.0f);
        }
    }
}

// Round 8
// 972.832 us; speedup vs baseline: 1.1438x; 1.1438x over previous
//
#include <hip/hip_runtime.h>
#include <hip/hip_fp16.h>
#include <math.h>

#define BB 16
#define NP 196
#define HH 4
#define KVD 960
#define KP 224    // Qt K-pad (zero-filled cols 196..223 kill Kt's garbage tail)
#define LDK 200   // Kt row stride: unpadded (196 data + 4 zero), 400B = 16B-aligned

typedef __attribute__((ext_vector_type(8))) short s8v;
typedef __attribute__((ext_vector_type(8))) unsigned short u8v;
typedef __attribute__((ext_vector_type(4))) unsigned short u4v;
typedef __attribute__((ext_vector_type(4))) float f4v;

static inline int divup(int a, int b){ return (a+b-1)/b; }
static inline int imin(int a, int b){ return a < b ? a : b; }

__device__ __forceinline__ unsigned short bf16r(float x){
    unsigned int u = __float_as_uint(x);
    u += 0x7fffu + ((u >> 16) & 1u);       // round-to-nearest-even
    return (unsigned short)(u >> 16);
}
__device__ __forceinline__ float bf16f(unsigned short h){
    return __uint_as_float(((unsigned int)h) << 16);
}

// async global->LDS, 16B per lane; LDS dest = uniform base + lane*16
__device__ __forceinline__ void gload16(const unsigned short* g, unsigned short* l){
    __builtin_amdgcn_global_load_lds(
        (const __attribute__((address_space(1))) void*)g,
        (__attribute__((address_space(3))) void*)l, 16, 0, 0);
}

// ---------------------------------------------------------------------------
// one-shot decompose of all 15 fp32 inputs -> bf16 (hi,lo) pairs.
// ---------------------------------------------------------------------------
struct DecTable {
    const float* src[15];
    unsigned short* dh[15];
    unsigned short* dl[15];
    long n4[15];
};

__global__ __launch_bounds__(256)
void decomp_all(DecTable T)
{
    int seg = blockIdx.y;
    const float* x = T.src[seg];
    unsigned short* hi = T.dh[seg];
    unsigned short* lo = T.dl[seg];
    long n4 = T.n4[seg];
    for (long i = (long)blockIdx.x * 256 + threadIdx.x; i < n4; i += (long)gridDim.x * 256) {
        float4 v = ((const float4*)x)[i];
        float a[4] = {v.x, v.y, v.z, v.w};
        u4v h, l;
#pragma unroll
        for (int e = 0; e < 4; e++) {
            unsigned short hb = bf16r(a[e]);
            h[e] = hb;
            l[e] = bf16r(a[e] - bf16f(hb));
        }
        *(u4v*)(hi + i * 4) = h;
        *(u4v*)(lo + i * 4) = l;
    }
}

// ---------------------------------------------------------------------------
// Split-bf16 NT GEMM via MFMA: C[M,Nn] = alpha * A[M,Kk] * B[Nn,Kk]^T
// OUTK: 0 = fp32 (Cf); 1 = bf16 hi/lo split (Ch,Cl) with zero pad to ldC;
//       2 = fp16 (Ch as raw half bits) -- used for the S buffer.
// STATS=1: per-block partial sum/sumsq -> part[z*64 + slot*2], slot=bx+gx*by
// ---------------------------------------------------------------------------
template<int OUTK, int STATS>
__global__ __launch_bounds__(256)
void gemm_split(const unsigned short* __restrict__ Ah, const unsigned short* __restrict__ Al,
                const unsigned short* __restrict__ Bh, const unsigned short* __restrict__ Bl,
                float* __restrict__ Cf, unsigned short* __restrict__ Ch,
                unsigned short* __restrict__ Cl, double* __restrict__ part,
                int M, int Nn, int Kk, int ldA, int ldB, int ldC,
                long sAb, long sAh_, long sBb, long sBh_, long sCb, long sCh_,
                int Hdiv, float alpha)
{
    __shared__ u8v AsV[128 * 8];
    __shared__ u8v BsV[128 * 8];
    unsigned short* As = (unsigned short*)AsV;
    unsigned short* Bs = (unsigned short*)BsV;

    int z  = blockIdx.z;
    int bb = z / Hdiv, hz = z - bb * Hdiv;
    const unsigned short* gah = Ah + (long)bb * sAb + (long)hz * sAh_;
    const unsigned short* gal = Al + (long)bb * sAb + (long)hz * sAh_;
    const unsigned short* gbh = Bh + (long)bb * sBb + (long)hz * sBh_;
    const unsigned short* gbl = Bl + (long)bb * sBb + (long)hz * sBh_;
    long coff = (long)bb * sCb + (long)hz * sCh_;

    int t = threadIdx.x;
    int m0 = blockIdx.y * 128, n0 = blockIdx.x * 128;
    int wave = t >> 6, lane = t & 63;
    int wm = wave >> 1, wn = wave & 1;
    int lr = lane & 15, lk = lane >> 4;

    int ls   = (lane & 7) ^ (lane >> 3);
    int comp = ls >> 2;
    int chnk = ls & 3;
    const unsigned short* gA = comp ? gal : gah;
    const unsigned short* gB = comp ? gbl : gbh;
    const unsigned short* aptr[4];
    const unsigned short* bptr[4];
#pragma unroll
    for (int j = 0; j < 4; j++) {
        int ra = m0 + wave * 32 + j * 8 + (lane >> 3);
        ra = (ra < M) ? ra : (M - 1);
        aptr[j] = gA + (long)ra * ldA + chnk * 8;
        int rb = n0 + wave * 32 + j * 8 + (lane >> 3);
        rb = (rb < Nn) ? rb : (Nn - 1);
        bptr[j] = gB + (long)rb * ldB + chnk * 8;
    }

    f4v acc[4][4];
#pragma unroll
    for (int i = 0; i < 4; i++)
#pragma unroll
        for (int j = 0; j < 4; j++) acc[i][j] = (f4v){0.f, 0.f, 0.f, 0.f};

    int nkt = Kk >> 5;
    for (int kt = 0; kt < nkt; ++kt) {
        int k0 = kt << 5;
#pragma unroll
        for (int j = 0; j < 4; j++) {
            gload16(aptr[j] + k0, As + (wave * 4 + j) * 512);
            gload16(bptr[j] + k0, Bs + (wave * 4 + j) * 512);
        }
        __syncthreads();

        s8v afh[4], afl[4], bfh[4], bfl[4];
#pragma unroll
        for (int i = 0; i < 4; i++) {
            int rw = wm * 64 + i * 16 + lr;
            afh[i] = *(const s8v*)&As[rw * 64 + ((lk ^ (rw & 7)) << 3)];
            afl[i] = *(const s8v*)&As[rw * 64 + (((lk + 4) ^ (rw & 7)) << 3)];
            int cw = wn * 64 + i * 16 + lr;
            bfh[i] = *(const s8v*)&Bs[cw * 64 + ((lk ^ (cw & 7)) << 3)];
            bfl[i] = *(const s8v*)&Bs[cw * 64 + (((lk + 4) ^ (cw & 7)) << 3)];
        }
#pragma unroll
        for (int i = 0; i < 4; i++)
#pragma unroll
            for (int j = 0; j < 4; j++) {
                acc[i][j] = __builtin_amdgcn_mfma_f32_16x16x32_bf16(afh[i], bfh[j], acc[i][j], 0, 0, 0);
                acc[i][j] = __builtin_amdgcn_mfma_f32_16x16x32_bf16(afl[i], bfh[j], acc[i][j], 0, 0, 0);
                acc[i][j] = __builtin_amdgcn_mfma_f32_16x16x32_bf16(afh[i], bfl[j], acc[i][j], 0, 0, 0);
            }
        __syncthreads();
    }

    float s1 = 0.f, s2 = 0.f;
#pragma unroll
    for (int i = 0; i < 4; i++)
#pragma unroll
        for (int j = 0; j < 4; j++)
#pragma unroll
            for (int r = 0; r < 4; r++) {
                int gr = m0 + wm * 64 + i * 16 + lk * 4 + r;
                int gc = n0 + wn * 64 + j * 16 + lr;
                if (gr < M) {
                    if (gc < Nn) {
                        float v = acc[i][j][r] * alpha;
                        if (STATS) { s1 += v; s2 += v * v; }
                        if (OUTK == 1) {
                            unsigned short hb = bf16r(v);
                            Ch[coff + (long)gr * ldC + gc] = hb;
                            Cl[coff + (long)gr * ldC + gc] = bf16r(v - bf16f(hb));
                        } else if (OUTK == 2) {
                            __half hh = __float2half(v);
                            unsigned short us;
                            __builtin_memcpy(&us, &hh, 2);
                            Ch[coff + (long)gr * ldC + gc] = us;
                        } else {
                            Cf[coff + (long)gr * ldC + gc] = v;
                        }
                    } else if (OUTK == 1 && gc < ldC) {
                        Ch[coff + (long)gr * ldC + gc] = 0;
                        Cl[coff + (long)gr * ldC + gc] = 0;
                    }
                }
            }

    if (STATS) {
        double* sh = (double*)AsV;
        sh[t] = (double)s1; sh[256 + t] = (double)s2;
        __syncthreads();
        for (int o = 128; o > 0; o >>= 1) {
            if (t < o) { sh[t] += sh[t + o]; sh[256 + t] += sh[256 + t + o]; }
            __syncthreads();
        }
        if (t == 0) {
            int slot = blockIdx.x + (int)gridDim.x * blockIdx.y;
            part[(long)z * 64 + slot * 2 + 0] = sh[0];
            part[(long)z * 64 + slot * 2 + 1] = sh[256];
        }
    }
}

// ---------------------------------------------------------------------------
// Fused softmax+PV: ctx[c,196] = softmax_kv((S-mu)*is) @ V^T, per map.
// S is fp16. Stats from per-block slots. V: [bh][196][960].
// ---------------------------------------------------------------------------
__global__ __launch_bounds__(256)
void pv_fused(const unsigned short* __restrict__ Sb, const unsigned short* __restrict__ Vh,
              const unsigned short* __restrict__ Vl, const double* __restrict__ part,
              float* __restrict__ Cb, int c, int m0, int nslot)
{
    __shared__ unsigned short As[64 * 64];    // P tile: 64 rows x 32kv (hi|lo), XOR-swizzled
    __shared__ unsigned short Bs[224 * 64];   // V tile: 224 cols x 32kv (hi|lo)
    __shared__ float Zlds[64];
    __shared__ float bc2[2];

    int z  = blockIdx.z;
    int gm = m0 + z;
    int my0 = blockIdx.y * 64;

    int t = threadIdx.x;
    int wave = t >> 6, lane = t & 63;
    int wm = wave >> 1, wn = wave & 1;
    int lr = lane & 15, lk = lane >> 4;

    if (t == 0) {
        const double* pp = part + (long)gm * 64;
        double su = 0.0, sq = 0.0;
        for (int q = 0; q < nslot; q++) { su += pp[q * 2]; sq += pp[q * 2 + 1]; }
        float inv_e = 1.0f / (float)(c * KVD);
        float mean = (float)(su * (double)inv_e);
        float var  = (float)(sq * (double)inv_e) - mean * mean;
        float is   = rsqrtf(var + 1e-5f);
        bc2[0] = is; bc2[1] = -mean * is;
    }
    __syncthreads();
    float is = bc2[0], dd = bc2[1];

    // A (P) staging map: thread t -> row t>>2, 8-kv chunk t&3 (fp16 S source)
    int arow = t >> 2, achk = t & 3;
    const unsigned short* sp = Sb + (size_t)z * c * KVD + (size_t)(my0 + arow) * KVD + achk * 8;
    unsigned short* awh = &As[arow * 64 + (( achk      ^ (arow & 7)) << 3)];
    unsigned short* awl = &As[arow * 64 + (((achk + 4) ^ (arow & 7)) << 3)];

    // B (V) staging: 7 gload16 per thread (224 rows x 128B)
    int ls   = (lane & 7) ^ (lane >> 3);
    int comp = ls >> 2, chnk = ls & 3;
    const unsigned short* vbase = (comp ? Vl : Vh) + (long)gm * (196L * KVD);
    const unsigned short* bptr[7];
    unsigned short* bdst[7];
#pragma unroll
    for (int q = 0; q < 7; q++) {
        int rlog = (wave * 7 + q) * 8 + (lane >> 3);
        int vrow = (rlog < NP) ? rlog : (NP - 1);
        bptr[q] = vbase + (long)vrow * KVD + chnk * 8;
        bdst[q] = &Bs[(wave * 7 + q) * 512];
    }

    f4v acc[2][7];
#pragma unroll
    for (int i = 0; i < 2; i++)
#pragma unroll
        for (int j = 0; j < 7; j++) acc[i][j] = (f4v){0.f, 0.f, 0.f, 0.f};
    float zp = 0.f;

    for (int kt = 0; kt < 30; ++kt) {
        int k0 = kt << 5;
#pragma unroll
        for (int q = 0; q < 7; q++) gload16(bptr[q] + k0, bdst[q]);

        u8v sv = *(const u8v*)(sp + k0);
        u8v hv, lv;
#pragma unroll
        for (int e = 0; e < 8; e++) {
            __half hh;
            unsigned short us = sv[e];
            __builtin_memcpy(&hh, &us, 2);
            float p = __expf(fmaf(__half2float(hh), is, dd));
            zp += p;
            unsigned short hb = bf16r(p);
            hv[e] = hb;
            lv[e] = bf16r(p - bf16f(hb));
        }
        *(u8v*)awh = hv;
        *(u8v*)awl = lv;
        __syncthreads();

        s8v afh[2], afl[2], bfh[7], bfl[7];
#pragma unroll
        for (int i = 0; i < 2; i++) {
            int ar = wm * 32 + i * 16 + lr;
            afh[i] = *(const s8v*)&As[ar * 64 + ((lk ^ (ar & 7)) << 3)];
            afl[i] = *(const s8v*)&As[ar * 64 + (((lk + 4) ^ (ar & 7)) << 3)];
        }
#pragma unroll
        for (int j = 0; j < 7; j++) {
            int br = wn * 112 + j * 16 + lr;
            bfh[j] = *(const s8v*)&Bs[br * 64 + ((lk ^ (br & 7)) << 3)];
            bfl[j] = *(const s8v*)&Bs[br * 64 + (((lk + 4) ^ (br & 7)) << 3)];
        }
#pragma unroll
        for (int i = 0; i < 2; i++)
#pragma unroll
            for (int j = 0; j < 7; j++) {
                acc[i][j] = __builtin_amdgcn_mfma_f32_16x16x32_bf16(afh[i], bfh[j], acc[i][j], 0, 0, 0);
                acc[i][j] = __builtin_amdgcn_mfma_f32_16x16x32_bf16(afl[i], bfh[j], acc[i][j], 0, 0, 0);
                acc[i][j] = __builtin_amdgcn_mfma_f32_16x16x32_bf16(afh[i], bfl[j], acc[i][j], 0, 0, 0);
            }
        __syncthreads();
    }

    zp += __shfl_xor(zp, 1);
    zp += __shfl_xor(zp, 2);
    if ((t & 3) == 0) Zlds[arow] = zp;
    __syncthreads();

    float rz[2][4];
#pragma unroll
    for (int i = 0; i < 2; i++)
#pragma unroll
        for (int r = 0; r < 4; r++)
            rz[i][r] = 1.0f / Zlds[wm * 32 + i * 16 + lk * 4 + r];

    float* co = Cb + (size_t)gm * c * NP;
#pragma unroll
    for (int i = 0; i < 2; i++)
#pragma unroll
        for (int j = 0; j < 7; j++)
#pragma unroll
            for (int r = 0; r < 4; r++) {
                int grl = wm * 32 + i * 16 + lk * 4 + r;
                int gc  = wn * 112 + j * 16 + lr;
                if (gc < NP)
                    co[(size_t)(my0 + grl) * NP + gc] = acc[i][j][r] * rz[i][r];
            }
}

// ---------------------------------------------------------------------------
// head-mean + transpose: Mb[b,n,d] = 0.25 * sum_h Cb[(b*4+h), d, n], split out.
// ---------------------------------------------------------------------------
__global__ __launch_bounds__(256)
void mean_t_kernel(const float* __restrict__ Cb, unsigned short* __restrict__ Mh,
                   unsigned short* __restrict__ Ml, int c)
{
    int b  = blockIdx.z;
    int n0 = blockIdx.x * 32;
    int d0 = blockIdx.y * 32;
    __shared__ float tile[32][33];
    int tx = threadIdx.x & 31;
    int ty = threadIdx.x >> 5;
#pragma unroll
    for (int i = 0; i < 4; i++) {
        int d = d0 + ty + i * 8;
        int n = n0 + tx;
        float s = 0.f;
        if (n < NP) {
#pragma unroll
            for (int h = 0; h < HH; h++)
                s += Cb[(((long)(b * HH + h)) * c + d) * NP + n];
        }
        tile[ty + i * 8][tx] = 0.25f * s;
    }
    __syncthreads();
#pragma unroll
    for (int i = 0; i < 4; i++) {
        int n = n0 + ty + i * 8;
        int d = d0 + tx;
        if (n < NP) {
            float val = tile[tx][ty + i * 8];
            long idx = ((long)b * NP + n) * c + d;
            unsigned short hb = bf16r(val);
            Mh[idx] = hb;
            Ml[idx] = bf16r(val - bf16f(hb));
        }
    }
}

// ---------------------------------------------------------------------------
extern "C" void kernel_launch(void* const* d_in, const int* in_sizes, int n_in,
                              void* d_out, int out_size, void* d_ws, size_t ws_size,
                              hipStream_t stream)
{
    const float* embf[4] = {(const float*)d_in[0], (const float*)d_in[1],
                            (const float*)d_in[2], (const float*)d_in[3]};
    const float* emb_all = (const float*)d_in[4];
    const float* Wq[4]   = {(const float*)d_in[5], (const float*)d_in[6],
                            (const float*)d_in[7], (const float*)d_in[8]};
    const float* Wk = (const float*)d_in[9];
    const float* Wv = (const float*)d_in[10];
    const float* Wo[4]   = {(const float*)d_in[11], (const float*)d_in[12],
                            (const float*)d_in[13], (const float*)d_in[14]};
    float* out = (float*)d_out;

    const int Cc[4] = {64, 128, 256, 512};

    char* base = (char*)d_ws;
    size_t off = 0;
    auto align256 = [](size_t b) -> size_t { return (b + 255) & ~(size_t)255; };
    auto carve = [&](size_t bytes) -> void* {
        void* p = base + off;
        off += align256(bytes);
        return p;
    };

    const long NEA   = (long)BB * NP * KVD;
    const long NWKV  = (long)HH * KVD * KVD;
    const long SUMC2 = 64L*64 + 128L*128 + 256L*256 + 512L*512;

    // ---- fixed: split weights + split emb_i + stats slots ----
    unsigned short* wkH = (unsigned short*)carve(NWKV * 2);
    unsigned short* wkL = (unsigned short*)carve(NWKV * 2);
    unsigned short* wvH = (unsigned short*)carve(NWKV * 2);
    unsigned short* wvL = (unsigned short*)carve(NWKV * 2);
    unsigned short* wqH = (unsigned short*)carve((long)HH * SUMC2 * 2);
    unsigned short* wqL = (unsigned short*)carve((long)HH * SUMC2 * 2);
    unsigned short* woH = (unsigned short*)carve(SUMC2 * 2);
    unsigned short* woL = (unsigned short*)carve(SUMC2 * 2);
    unsigned short* eiH = (unsigned short*)carve(NEA * 2);   // all 4 emb_i concatenated
    unsigned short* eiL = (unsigned short*)carve(NEA * 2);
    double* part = (double*)carve(64L * 64 * 8);             // [map][32 slots][2]

    size_t fixed_off = off;
    const size_t eaBytes = 2 * align256(NEA * 2);            // emb_all hi+lo

    auto group_bytes = [&](int gb) -> size_t {
        long nbh = (long)gb * HH;
        size_t s = 0;
        auto add = [&](size_t b){ s += align256(b); };
        add(nbh * KVD * LDK * 2 + 512); add(nbh * KVD * LDK * 2 + 512);  // Kt hi/lo (ld=200, +slack)
        add(nbh * NP * KVD * 2); add(nbh * NP * KVD * 2);    // V hi/lo
        add(nbh * 512 * KP * 2); add(nbh * 512 * KP * 2);    // Qt hi/lo
        add(nbh * 512 * NP * 4);                             // Cb fp32
        add((long)gb * NP * 512 * 2); add((long)gb * NP * 512 * 2); // Mb hi/lo
        return s;
    };

    // GB selection. GB=16: emb_all split lives in the chunk zone (dead before
    // any S work -> S chunks may overwrite it). GB<16: ea must persist across
    // group passes -> carve it in the fixed region.
    int GB;
    bool eaChunk;
    if (fixed_off + group_bytes(16) + eaBytes + (2u << 20) <= ws_size) {
        GB = 16; eaChunk = true;
    } else {
        eaChunk = false;
        const size_t minchunk = (size_t)512 * KVD * 2 + (1u << 20);  // 1 fp16 S map @ c=512
        GB = 8;
        while (GB > 1 && fixed_off + eaBytes + group_bytes(GB) + minchunk > ws_size) GB >>= 1;
    }
    unsigned short* eaH = nullptr;
    unsigned short* eaL = nullptr;
    if (!eaChunk) {
        eaH = (unsigned short*)carve(NEA * 2);
        eaL = (unsigned short*)carve(NEA * 2);
    }
    const long NBH = (long)GB * HH;

    unsigned short* KtH = (unsigned short*)carve(NBH * KVD * LDK * 2 + 512); // [bh][960][200]
    unsigned short* KtL = (unsigned short*)carve(NBH * KVD * LDK * 2 + 512);
    unsigned short* VH  = (unsigned short*)carve(NBH * NP * KVD * 2);        // [bh][196][960]
    unsigned short* VL  = (unsigned short*)carve(NBH * NP * KVD * 2);
    unsigned short* QtH = (unsigned short*)carve(NBH * 512 * KP * 2);        // [b][4c][224]
    unsigned short* QtL = (unsigned short*)carve(NBH * 512 * KP * 2);
    float*  Cb          = (float*)carve(NBH * 512 * NP * 4);                 // [bh][c][196]
    unsigned short* MbH = (unsigned short*)carve((long)GB * NP * 512 * 2);
    unsigned short* MbL = (unsigned short*)carve((long)GB * NP * 512 * 2);

    char* chunk = base + off;
    size_t savail = (ws_size > off) ? (ws_size - off) : 0;
    if (eaChunk) {
        eaH = (unsigned short*)chunk;
        eaL = (unsigned short*)(chunk + align256(NEA * 2));
    }

    dim3 blk(256);
    const float alphaS = 1.0f / sqrtf((float)KVD);

    // ---- one-shot decompose of all inputs ----
    long eio[4], wqo[4], woo[4];
    { long eo = 0, qo = 0, oo = 0;
      for (int i = 0; i < 4; i++) {
          eio[i] = eo; eo += (long)BB * NP * Cc[i];
          wqo[i] = qo; qo += (long)HH * Cc[i] * Cc[i];
          woo[i] = oo; oo += (long)Cc[i] * Cc[i];
      } }
    {
        DecTable T;
        int k = 0;
        for (int i = 0; i < 4; i++) {
            T.src[k] = embf[i]; T.dh[k] = eiH + eio[i]; T.dl[k] = eiL + eio[i];
            T.n4[k] = ((long)BB * NP * Cc[i]) / 4; k++;
        }
        T.src[k] = emb_all; T.dh[k] = eaH; T.dl[k] = eaL; T.n4[k] = NEA / 4; k++;
        for (int i = 0; i < 4; i++) {
            T.src[k] = Wq[i]; T.dh[k] = wqH + wqo[i]; T.dl[k] = wqL + wqo[i];
            T.n4[k] = ((long)HH * Cc[i] * Cc[i]) / 4; k++;
        }
        T.src[k] = Wk; T.dh[k] = wkH; T.dl[k] = wkL; T.n4[k] = NWKV / 4; k++;
        T.src[k] = Wv; T.dh[k] = wvH; T.dl[k] = wvL; T.n4[k] = NWKV / 4; k++;
        for (int i = 0; i < 4; i++) {
            T.src[k] = Wo[i]; T.dh[k] = woH + woo[i]; T.dl[k] = woL + woo[i];
            T.n4[k] = ((long)Cc[i] * Cc[i]) / 4; k++;
        }
        decomp_all<<<dim3(512, 15, 1), blk, 0, stream>>>(T);
    }

    long obase[4];
    { long o = 0; for (int i = 0; i < 4; i++) { obase[i] = o; o += (long)BB * NP * Cc[i]; } }

    // ---- batch-group passes ----
    for (int g0 = 0; g0 < BB; g0 += GB) {
        const unsigned short* eaHg = eaH + (long)g0 * NP * KVD;
        const unsigned short* eaLg = eaL + (long)g0 * NP * KVD;

        // Kt[bh][960][200] = Wk[h] @ emb_all[b]^T  (cols 196..199 zeroed; tail
        // 200..223 read by S staging is garbage but multiplied by Qt's zero pad)
        gemm_split<1,0><<<dim3(2, 8, (int)NBH), blk, 0, stream>>>(
            wkH, wkL, eaHg, eaLg, nullptr, KtH, KtL, nullptr,
            KVD, NP, KVD, KVD, KVD, LDK,
            0, (long)KVD * KVD, (long)NP * KVD, 0,
            (long)HH * KVD * LDK, (long)KVD * LDK, HH, 1.0f);

        // V[bh][196][960] = emb_all[b] @ Wv[h]^T
        gemm_split<1,0><<<dim3(8, 2, (int)NBH), blk, 0, stream>>>(
            eaHg, eaLg, wvH, wvL, nullptr, VH, VL, nullptr,
            NP, KVD, KVD, KVD, KVD, KVD,
            (long)NP * KVD, 0, 0, (long)KVD * KVD,
            (long)HH * NP * KVD, (long)NP * KVD, HH, 1.0f);

        for (int i = 0; i < 4; i++) {
            int c = Cc[i];

            // Qt[b][4c][224] = Wq_all_i @ emb_i[b]^T  (zero-padded cols)
            gemm_split<1,0><<<dim3(2, divup(HH * c, 128), GB), blk, 0, stream>>>(
                wqH + wqo[i], wqL + wqo[i],
                eiH + eio[i] + (long)g0 * NP * c, eiL + eio[i] + (long)g0 * NP * c,
                nullptr, QtH, QtL, nullptr,
                HH * c, NP, c, c, c, KP,
                0, 0, (long)NP * c, 0,
                (long)HH * c * KP, 0, 1, 1.0f);

            int nslot = 8 * divup(c, 128);

            size_t per = (size_t)c * KVD * 2;   // fp16 S per map
            int G = (savail >= per) ? (int)(savail / per) : 1;
            if (G > (int)NBH) G = (int)NBH;
            if (G < 1) G = 1;
            unsigned short* Sb = (unsigned short*)chunk;

            for (int m0 = 0; m0 < (int)NBH; m0 += G) {
                int g = imin(G, (int)NBH - m0);
                // S[c,960] (fp16) = (Qt @ Kt^T)/sqrt(960); per-block stats slots
                gemm_split<2,1><<<dim3(8, divup(c, 128), g), blk, 0, stream>>>(
                    QtH + (size_t)m0 * c * KP, QtL + (size_t)m0 * c * KP,
                    KtH + (size_t)m0 * KVD * LDK, KtL + (size_t)m0 * KVD * LDK,
                    nullptr, Sb, nullptr, part + (size_t)m0 * 64,
                    c, KVD, KP, KP, LDK, KVD,
                    (long)c * KP, 0, (long)KVD * LDK, 0, (long)c * KVD, 0,
                    1, alphaS);
                // fused exp/Z/PV -> ctx fp32
                pv_fused<<<dim3(1, c / 64, g), blk, 0, stream>>>(
                    Sb, VH, VL, part, Cb, c, m0, nslot);
            }
            // head-mean + transpose -> split Mb[b_local,n,d]
            mean_t_kernel<<<dim3(divup(NP, 32), c / 32, GB), blk, 0, stream>>>(Cb, MbH, MbL, c);
            // O rows for this group = Mb @ Wo^T
            gemm_split<0,0><<<dim3(divup(c, 128), divup(GB * NP, 128), 1), blk, 0, stream>>>(
                MbH, MbL, woH + woo[i], woL + woo[i],
                out + obase[i] + (long)g0 * NP * c, nullptr, nullptr, nullptr,
                GB * NP, c, c, c, c, c,
                0, 0, 0, 0, 0, 0, 1, 1.0f);
        }
    }
}

// Round 9
// 918.094 us; speedup vs baseline: 1.2120x; 1.0596x over previous
//
#include <hip/hip_runtime.h>
#include <hip/hip_fp16.h>
#include <math.h>

#define BB 16
#define NP 196
#define HH 4
#define KVD 960
#define KP 224    // Qt K-pad (zero cols 196..223 kill Kt's garbage tail)
#define LDK 200   // Kt row stride (196 data + 4 zero), 400B = 16B-aligned
#define SM 960    // stacked M: 512+256+128+64, branch bounds 512/768/896 all %128==0

typedef __attribute__((ext_vector_type(8))) short s8v;
typedef __attribute__((ext_vector_type(8))) unsigned short u8v;
typedef __attribute__((ext_vector_type(4))) unsigned short u4v;
typedef __attribute__((ext_vector_type(4))) float f4v;

static inline int divup(int a, int b){ return (a+b-1)/b; }
static inline int imin(int a, int b){ return a < b ? a : b; }

__device__ __forceinline__ unsigned short bf16r(float x){
    unsigned int u = __float_as_uint(x);
    u += 0x7fffu + ((u >> 16) & 1u);       // round-to-nearest-even
    return (unsigned short)(u >> 16);
}
__device__ __forceinline__ float bf16f(unsigned short h){
    return __uint_as_float(((unsigned int)h) << 16);
}

__device__ __forceinline__ void gload16(const unsigned short* g, unsigned short* l){
    __builtin_amdgcn_global_load_lds(
        (const __attribute__((address_space(1))) void*)g,
        (__attribute__((address_space(3))) void*)l, 16, 0, 0);
}

// ---------------------------------------------------------------------------
// one-shot decompose of all 15 fp32 inputs -> bf16 (hi,lo) pairs.
// ---------------------------------------------------------------------------
struct DecTable {
    const float* src[15];
    unsigned short* dh[15];
    unsigned short* dl[15];
    long n4[15];
};

__global__ __launch_bounds__(256)
void decomp_all(DecTable T)
{
    int seg = blockIdx.y;
    const float* x = T.src[seg];
    unsigned short* hi = T.dh[seg];
    unsigned short* lo = T.dl[seg];
    long n4 = T.n4[seg];
    for (long i = (long)blockIdx.x * 256 + threadIdx.x; i < n4; i += (long)gridDim.x * 256) {
        float4 v = ((const float4*)x)[i];
        float a[4] = {v.x, v.y, v.z, v.w};
        u4v h, l;
#pragma unroll
        for (int e = 0; e < 4; e++) {
            unsigned short hb = bf16r(a[e]);
            h[e] = hb;
            l[e] = bf16r(a[e] - bf16f(hb));
        }
        *(u4v*)(hi + i * 4) = h;
        *(u4v*)(lo + i * 4) = l;
    }
}

// ---------------------------------------------------------------------------
// Split-bf16 NT GEMM via MFMA: C[M,Nn] = alpha * A[M,Kk] * B[Nn,Kk]^T
// OUTK: 0 = fp32; 1 = bf16 hi/lo split with zero pad to ldC; 2 = fp16.
// STATS=1: per-block partial sum/sumsq -> part[z*128 + slot*2], slot=bx+8*by
//          (stacked-M S: each 128-row block belongs to exactly one branch)
// ---------------------------------------------------------------------------
template<int OUTK, int STATS>
__global__ __launch_bounds__(256)
void gemm_split(const unsigned short* __restrict__ Ah, const unsigned short* __restrict__ Al,
                const unsigned short* __restrict__ Bh, const unsigned short* __restrict__ Bl,
                float* __restrict__ Cf, unsigned short* __restrict__ Ch,
                unsigned short* __restrict__ Cl, double* __restrict__ part,
                int M, int Nn, int Kk, int ldA, int ldB, int ldC,
                long sAb, long sAh_, long sBb, long sBh_, long sCb, long sCh_,
                int Hdiv, float alpha)
{
    __shared__ u8v AsV[128 * 8];
    __shared__ u8v BsV[128 * 8];
    unsigned short* As = (unsigned short*)AsV;
    unsigned short* Bs = (unsigned short*)BsV;

    int z  = blockIdx.z;
    int bb = z / Hdiv, hz = z - bb * Hdiv;
    const unsigned short* gah = Ah + (long)bb * sAb + (long)hz * sAh_;
    const unsigned short* gal = Al + (long)bb * sAb + (long)hz * sAh_;
    const unsigned short* gbh = Bh + (long)bb * sBb + (long)hz * sBh_;
    const unsigned short* gbl = Bl + (long)bb * sBb + (long)hz * sBh_;
    long coff = (long)bb * sCb + (long)hz * sCh_;

    int t = threadIdx.x;
    int m0 = blockIdx.y * 128, n0 = blockIdx.x * 128;
    int wave = t >> 6, lane = t & 63;
    int wm = wave >> 1, wn = wave & 1;
    int lr = lane & 15, lk = lane >> 4;

    int ls   = (lane & 7) ^ (lane >> 3);
    int comp = ls >> 2;
    int chnk = ls & 3;
    const unsigned short* gA = comp ? gal : gah;
    const unsigned short* gB = comp ? gbl : gbh;
    const unsigned short* aptr[4];
    const unsigned short* bptr[4];
#pragma unroll
    for (int j = 0; j < 4; j++) {
        int ra = m0 + wave * 32 + j * 8 + (lane >> 3);
        ra = (ra < M) ? ra : (M - 1);
        aptr[j] = gA + (long)ra * ldA + chnk * 8;
        int rb = n0 + wave * 32 + j * 8 + (lane >> 3);
        rb = (rb < Nn) ? rb : (Nn - 1);
        bptr[j] = gB + (long)rb * ldB + chnk * 8;
    }

    f4v acc[4][4];
#pragma unroll
    for (int i = 0; i < 4; i++)
#pragma unroll
        for (int j = 0; j < 4; j++) acc[i][j] = (f4v){0.f, 0.f, 0.f, 0.f};

    int nkt = Kk >> 5;
    for (int kt = 0; kt < nkt; ++kt) {
        int k0 = kt << 5;
#pragma unroll
        for (int j = 0; j < 4; j++) {
            gload16(aptr[j] + k0, As + (wave * 4 + j) * 512);
            gload16(bptr[j] + k0, Bs + (wave * 4 + j) * 512);
        }
        __syncthreads();

        s8v afh[4], afl[4], bfh[4], bfl[4];
#pragma unroll
        for (int i = 0; i < 4; i++) {
            int rw = wm * 64 + i * 16 + lr;
            afh[i] = *(const s8v*)&As[rw * 64 + ((lk ^ (rw & 7)) << 3)];
            afl[i] = *(const s8v*)&As[rw * 64 + (((lk + 4) ^ (rw & 7)) << 3)];
            int cw = wn * 64 + i * 16 + lr;
            bfh[i] = *(const s8v*)&Bs[cw * 64 + ((lk ^ (cw & 7)) << 3)];
            bfl[i] = *(const s8v*)&Bs[cw * 64 + (((lk + 4) ^ (cw & 7)) << 3)];
        }
#pragma unroll
        for (int i = 0; i < 4; i++)
#pragma unroll
            for (int j = 0; j < 4; j++) {
                acc[i][j] = __builtin_amdgcn_mfma_f32_16x16x32_bf16(afh[i], bfh[j], acc[i][j], 0, 0, 0);
                acc[i][j] = __builtin_amdgcn_mfma_f32_16x16x32_bf16(afl[i], bfh[j], acc[i][j], 0, 0, 0);
                acc[i][j] = __builtin_amdgcn_mfma_f32_16x16x32_bf16(afh[i], bfl[j], acc[i][j], 0, 0, 0);
            }
        __syncthreads();
    }

    float s1 = 0.f, s2 = 0.f;
#pragma unroll
    for (int i = 0; i < 4; i++)
#pragma unroll
        for (int j = 0; j < 4; j++)
#pragma unroll
            for (int r = 0; r < 4; r++) {
                int gr = m0 + wm * 64 + i * 16 + lk * 4 + r;
                int gc = n0 + wn * 64 + j * 16 + lr;
                if (gr < M) {
                    if (gc < Nn) {
                        float v = acc[i][j][r] * alpha;
                        if (STATS) { s1 += v; s2 += v * v; }
                        if (OUTK == 1) {
                            unsigned short hb = bf16r(v);
                            Ch[coff + (long)gr * ldC + gc] = hb;
                            Cl[coff + (long)gr * ldC + gc] = bf16r(v - bf16f(hb));
                        } else if (OUTK == 2) {
                            __half hh = __float2half(v);
                            unsigned short us;
                            __builtin_memcpy(&us, &hh, 2);
                            Ch[coff + (long)gr * ldC + gc] = us;
                        } else {
                            Cf[coff + (long)gr * ldC + gc] = v;
                        }
                    } else if (OUTK == 1 && gc < ldC) {
                        Ch[coff + (long)gr * ldC + gc] = 0;
                        Cl[coff + (long)gr * ldC + gc] = 0;
                    }
                }
            }

    if (STATS) {
        double* sh = (double*)AsV;
        sh[t] = (double)s1; sh[256 + t] = (double)s2;
        __syncthreads();
        for (int o = 128; o > 0; o >>= 1) {
            if (t < o) { sh[t] += sh[t + o]; sh[256 + t] += sh[256 + t + o]; }
            __syncthreads();
        }
        if (t == 0) {
            int slot = blockIdx.x + (int)gridDim.x * blockIdx.y;   // 0..63
            part[(long)z * 128 + slot * 2 + 0] = sh[0];
            part[(long)z * 128 + slot * 2 + 1] = sh[256];
        }
    }
}

// ---------------------------------------------------------------------------
// Fused softmax+PV over the STACKED map: ctx rows [my0,my0+64) of the 960-row
// stack. Branch derived from my0 (bounds 512/768/896); stats summed from that
// branch's row-block slots. S fp16 [z][960][960]; V chunk-local [z][196][960];
// Cb fp16 global [bh][960][196].
// ---------------------------------------------------------------------------
__global__ __launch_bounds__(256)
void pv_fused(const unsigned short* __restrict__ Sb, const unsigned short* __restrict__ Vh,
              const unsigned short* __restrict__ Vl, const double* __restrict__ part,
              __half* __restrict__ Cb, int m0)
{
    __shared__ unsigned short As[64 * 64];
    __shared__ unsigned short Bs[224 * 64];
    __shared__ float Zlds[64];
    __shared__ float bc2[2];

    int z  = blockIdx.z;
    int gm = m0 + z;                 // global map
    int my0 = blockIdx.y * 64;       // stacked-row base (0..896)

    int t = threadIdx.x;
    int wave = t >> 6, lane = t & 63;
    int wm = wave >> 1, wn = wave & 1;
    int lr = lane & 15, lk = lane >> 4;

    if (t == 0) {
        int br = (my0 >= 896) ? 3 : (my0 >= 768) ? 2 : (my0 >= 512) ? 1 : 0;
        const int by0_[4] = {0, 4, 6, 7};
        const int nby_[4] = {4, 2, 1, 1};
        const int cbr_[4] = {512, 256, 128, 64};
        const double* pp = part + (long)z * 128;
        double su = 0.0, sq = 0.0;
        int q0 = 8 * by0_[br], q1 = 8 * (by0_[br] + nby_[br]);
        for (int q = q0; q < q1; q++) { su += pp[q * 2]; sq += pp[q * 2 + 1]; }
        float inv_e = 1.0f / (float)(cbr_[br] * KVD);
        float mean = (float)(su * (double)inv_e);
        float var  = (float)(sq * (double)inv_e) - mean * mean;
        float is   = rsqrtf(var + 1e-5f);
        bc2[0] = is; bc2[1] = -mean * is;
    }
    __syncthreads();
    float is = bc2[0], dd = bc2[1];

    // A (P) staging: thread t -> row t>>2, 8-kv chunk t&3 (fp16 S source)
    int arow = t >> 2, achk = t & 3;
    const unsigned short* sp = Sb + (size_t)z * SM * KVD + (size_t)(my0 + arow) * KVD + achk * 8;
    unsigned short* awh = &As[arow * 64 + (( achk      ^ (arow & 7)) << 3)];
    unsigned short* awl = &As[arow * 64 + (((achk + 4) ^ (arow & 7)) << 3)];

    // B (V) staging: 7 gload16 per thread (224 rows x 128B), chunk-local V
    int ls   = (lane & 7) ^ (lane >> 3);
    int comp = ls >> 2, chnk = ls & 3;
    const unsigned short* vbase = (comp ? Vl : Vh) + (long)z * (196L * KVD);
    const unsigned short* bptr[7];
    unsigned short* bdst[7];
#pragma unroll
    for (int q = 0; q < 7; q++) {
        int rlog = (wave * 7 + q) * 8 + (lane >> 3);
        int vrow = (rlog < NP) ? rlog : (NP - 1);
        bptr[q] = vbase + (long)vrow * KVD + chnk * 8;
        bdst[q] = &Bs[(wave * 7 + q) * 512];
    }

    f4v acc[2][7];
#pragma unroll
    for (int i = 0; i < 2; i++)
#pragma unroll
        for (int j = 0; j < 7; j++) acc[i][j] = (f4v){0.f, 0.f, 0.f, 0.f};
    float zp = 0.f;

    for (int kt = 0; kt < 30; ++kt) {
        int k0 = kt << 5;
#pragma unroll
        for (int q = 0; q < 7; q++) gload16(bptr[q] + k0, bdst[q]);

        u8v sv = *(const u8v*)(sp + k0);
        u8v hv, lv;
#pragma unroll
        for (int e = 0; e < 8; e++) {
            __half hh;
            unsigned short us = sv[e];
            __builtin_memcpy(&hh, &us, 2);
            float p = __expf(fmaf(__half2float(hh), is, dd));
            zp += p;
            unsigned short hb = bf16r(p);
            hv[e] = hb;
            lv[e] = bf16r(p - bf16f(hb));
        }
        *(u8v*)awh = hv;
        *(u8v*)awl = lv;
        __syncthreads();

        s8v afh[2], afl[2], bfh[7], bfl[7];
#pragma unroll
        for (int i = 0; i < 2; i++) {
            int ar = wm * 32 + i * 16 + lr;
            afh[i] = *(const s8v*)&As[ar * 64 + ((lk ^ (ar & 7)) << 3)];
            afl[i] = *(const s8v*)&As[ar * 64 + (((lk + 4) ^ (ar & 7)) << 3)];
        }
#pragma unroll
        for (int j = 0; j < 7; j++) {
            int br2 = wn * 112 + j * 16 + lr;
            bfh[j] = *(const s8v*)&Bs[br2 * 64 + ((lk ^ (br2 & 7)) << 3)];
            bfl[j] = *(const s8v*)&Bs[br2 * 64 + (((lk + 4) ^ (br2 & 7)) << 3)];
        }
#pragma unroll
        for (int i = 0; i < 2; i++)
#pragma unroll
            for (int j = 0; j < 7; j++) {
                acc[i][j] = __builtin_amdgcn_mfma_f32_16x16x32_bf16(afh[i], bfh[j], acc[i][j], 0, 0, 0);
                acc[i][j] = __builtin_amdgcn_mfma_f32_16x16x32_bf16(afl[i], bfh[j], acc[i][j], 0, 0, 0);
                acc[i][j] = __builtin_amdgcn_mfma_f32_16x16x32_bf16(afh[i], bfl[j], acc[i][j], 0, 0, 0);
            }
        __syncthreads();
    }

    zp += __shfl_xor(zp, 1);
    zp += __shfl_xor(zp, 2);
    if ((t & 3) == 0) Zlds[arow] = zp;
    __syncthreads();

    float rz[2][4];
#pragma unroll
    for (int i = 0; i < 2; i++)
#pragma unroll
        for (int r = 0; r < 4; r++)
            rz[i][r] = 1.0f / Zlds[wm * 32 + i * 16 + lk * 4 + r];

    __half* co = Cb + (size_t)gm * SM * NP;
#pragma unroll
    for (int i = 0; i < 2; i++)
#pragma unroll
        for (int j = 0; j < 7; j++)
#pragma unroll
            for (int r = 0; r < 4; r++) {
                int grl = wm * 32 + i * 16 + lk * 4 + r;
                int gc  = wn * 112 + j * 16 + lr;
                if (gc < NP)
                    co[(size_t)(my0 + grl) * NP + gc] = __float2half(acc[i][j][r] * rz[i][r]);
            }
}

// ---------------------------------------------------------------------------
// head-mean + transpose from the stacked fp16 Cb:
// Mb[b,n,d] = 0.25 * sum_h Cb[(b*4+h)][roff + d][n], split bf16 out.
// ---------------------------------------------------------------------------
__global__ __launch_bounds__(256)
void mean_t_kernel(const __half* __restrict__ Cb, unsigned short* __restrict__ Mh,
                   unsigned short* __restrict__ Ml, int c, int roff)
{
    int b  = blockIdx.z;
    int n0 = blockIdx.x * 32;
    int d0 = blockIdx.y * 32;
    __shared__ float tile[32][33];
    int tx = threadIdx.x & 31;
    int ty = threadIdx.x >> 5;
#pragma unroll
    for (int i = 0; i < 4; i++) {
        int d = d0 + ty + i * 8;
        int n = n0 + tx;
        float s = 0.f;
        if (n < NP) {
#pragma unroll
            for (int h = 0; h < HH; h++)
                s += __half2float(Cb[((long)(b * HH + h) * SM + roff + d) * NP + n]);
        }
        tile[ty + i * 8][tx] = 0.25f * s;
    }
    __syncthreads();
#pragma unroll
    for (int i = 0; i < 4; i++) {
        int n = n0 + ty + i * 8;
        int d = d0 + tx;
        if (n < NP) {
            float val = tile[tx][ty + i * 8];
            long idx = ((long)b * NP + n) * c + d;
            unsigned short hb = bf16r(val);
            Mh[idx] = hb;
            Ml[idx] = bf16r(val - bf16f(hb));
        }
    }
}

// ---------------------------------------------------------------------------
extern "C" void kernel_launch(void* const* d_in, const int* in_sizes, int n_in,
                              void* d_out, int out_size, void* d_ws, size_t ws_size,
                              hipStream_t stream)
{
    const float* embf[4] = {(const float*)d_in[0], (const float*)d_in[1],
                            (const float*)d_in[2], (const float*)d_in[3]};
    const float* emb_all = (const float*)d_in[4];
    const float* Wq[4]   = {(const float*)d_in[5], (const float*)d_in[6],
                            (const float*)d_in[7], (const float*)d_in[8]};
    const float* Wk = (const float*)d_in[9];
    const float* Wv = (const float*)d_in[10];
    const float* Wo[4]   = {(const float*)d_in[11], (const float*)d_in[12],
                            (const float*)d_in[13], (const float*)d_in[14]};
    float* out = (float*)d_out;

    const int Cc[4]   = {64, 128, 256, 512};
    const int roff[4] = {896, 768, 512, 0};   // stack row offset per branch (desc c)

    char* base = (char*)d_ws;
    size_t off = 0;
    auto align256 = [](size_t b) -> size_t { return (b + 255) & ~(size_t)255; };
    auto carve = [&](size_t bytes) -> void* {
        void* p = base + off;
        off += align256(bytes);
        return p;
    };

    const long NEA   = (long)BB * NP * KVD;
    const long NWKV  = (long)HH * KVD * KVD;
    const long SUMC2 = 64L*64 + 128L*128 + 256L*256 + 512L*512;
    const long NMAP  = (long)BB * HH;   // 64

    // ---- static region ----
    unsigned short* wkH = (unsigned short*)carve(NWKV * 2);
    unsigned short* wkL = (unsigned short*)carve(NWKV * 2);
    unsigned short* wvH = (unsigned short*)carve(NWKV * 2);
    unsigned short* wvL = (unsigned short*)carve(NWKV * 2);
    unsigned short* wqH = (unsigned short*)carve((long)HH * SUMC2 * 2);
    unsigned short* wqL = (unsigned short*)carve((long)HH * SUMC2 * 2);
    unsigned short* woH = (unsigned short*)carve(SUMC2 * 2);
    unsigned short* woL = (unsigned short*)carve(SUMC2 * 2);
    unsigned short* eiH = (unsigned short*)carve(NEA * 2);
    unsigned short* eiL = (unsigned short*)carve(NEA * 2);
    unsigned short* eaH = (unsigned short*)carve(NEA * 2);
    unsigned short* eaL = (unsigned short*)carve(NEA * 2);
    double* part = (double*)carve(64L * 128 * 8);            // [chunk-z][64 slots][2]
    __half* Cb   = (__half*)carve(NMAP * SM * NP * 2);       // stacked ctx, fp16
    unsigned short* MbH = (unsigned short*)carve((long)BB * NP * 512 * 2);
    unsigned short* MbL = (unsigned short*)carve((long)BB * NP * 512 * 2);

    size_t static_off = off;
    size_t zavail = (ws_size > static_off) ? (ws_size - static_off) : 0;

    // ---- per-chunk sizing (G maps, G multiple of 4) ----
    auto chunk_bytes = [&](int g) -> size_t {
        size_t s = 0;
        auto add = [&](size_t b){ s += align256(b); };
        add((size_t)g * KVD * LDK * 2 + 512); add((size_t)g * KVD * LDK * 2 + 512); // Kt
        add((size_t)g * NP * KVD * 2);        add((size_t)g * NP * KVD * 2);        // V
        add((size_t)g * SM * KP * 2);         add((size_t)g * SM * KP * 2);         // Qt
        add((size_t)g * SM * KVD * 2);                                              // S fp16
        return s;
    };
    int G = 64;
    while (G > 4 && chunk_bytes(G) > zavail) G -= 4;

    char* cz = base + static_off;
    size_t co2 = 0;
    auto czcarve = [&](size_t bytes) -> void* {
        void* p = cz + co2;
        co2 += align256(bytes);
        return p;
    };
    unsigned short* KtH = (unsigned short*)czcarve((size_t)G * KVD * LDK * 2 + 512);
    unsigned short* KtL = (unsigned short*)czcarve((size_t)G * KVD * LDK * 2 + 512);
    unsigned short* VH  = (unsigned short*)czcarve((size_t)G * NP * KVD * 2);
    unsigned short* VL  = (unsigned short*)czcarve((size_t)G * NP * KVD * 2);
    unsigned short* QtH = (unsigned short*)czcarve((size_t)G * SM * KP * 2);
    unsigned short* QtL = (unsigned short*)czcarve((size_t)G * SM * KP * 2);
    unsigned short* Sb  = (unsigned short*)czcarve((size_t)G * SM * KVD * 2);

    dim3 blk(256);
    const float alphaS = 1.0f / sqrtf((float)KVD);

    // ---- one-shot decompose of all inputs ----
    long eio[4], wqo[4], woo[4];
    { long eo = 0, qo = 0, oo = 0;
      for (int i = 0; i < 4; i++) {
          eio[i] = eo; eo += (long)BB * NP * Cc[i];
          wqo[i] = qo; qo += (long)HH * Cc[i] * Cc[i];
          woo[i] = oo; oo += (long)Cc[i] * Cc[i];
      } }
    {
        DecTable T;
        int k = 0;
        for (int i = 0; i < 4; i++) {
            T.src[k] = embf[i]; T.dh[k] = eiH + eio[i]; T.dl[k] = eiL + eio[i];
            T.n4[k] = ((long)BB * NP * Cc[i]) / 4; k++;
        }
        T.src[k] = emb_all; T.dh[k] = eaH; T.dl[k] = eaL; T.n4[k] = NEA / 4; k++;
        for (int i = 0; i < 4; i++) {
            T.src[k] = Wq[i]; T.dh[k] = wqH + wqo[i]; T.dl[k] = wqL + wqo[i];
            T.n4[k] = ((long)HH * Cc[i] * Cc[i]) / 4; k++;
        }
        T.src[k] = Wk; T.dh[k] = wkH; T.dl[k] = wkL; T.n4[k] = NWKV / 4; k++;
        T.src[k] = Wv; T.dh[k] = wvH; T.dl[k] = wvL; T.n4[k] = NWKV / 4; k++;
        for (int i = 0; i < 4; i++) {
            T.src[k] = Wo[i]; T.dh[k] = woH + woo[i]; T.dl[k] = woL + woo[i];
            T.n4[k] = ((long)Cc[i] * Cc[i]) / 4; k++;
        }
        decomp_all<<<dim3(512, 15, 1), blk, 0, stream>>>(T);
    }

    long obase[4];
    { long o = 0; for (int i = 0; i < 4; i++) { obase[i] = o; o += (long)BB * NP * Cc[i]; } }

    // ---- chunk loop over the 64 (b,h) maps ----
    for (int m0 = 0; m0 < (int)NMAP; m0 += G) {
        int g = imin(G, (int)NMAP - m0);         // multiple of 4
        int b0 = m0 / HH;                        // first batch of chunk

        // Kt[z][960][200] = Wk[h] @ emb_all[b]^T    (z-local; h=z%4, b=b0+z/4)
        gemm_split<1,0><<<dim3(2, 8, g), blk, 0, stream>>>(
            wkH, wkL, eaH + (long)b0 * NP * KVD, eaL + (long)b0 * NP * KVD,
            nullptr, KtH, KtL, nullptr,
            KVD, NP, KVD, KVD, KVD, LDK,
            0, (long)KVD * KVD, (long)NP * KVD, 0,
            (long)HH * KVD * LDK, (long)KVD * LDK, HH, 1.0f);

        // V[z][196][960] = emb_all[b] @ Wv[h]^T
        gemm_split<1,0><<<dim3(8, 2, g), blk, 0, stream>>>(
            eaH + (long)b0 * NP * KVD, eaL + (long)b0 * NP * KVD, wvH, wvL,
            nullptr, VH, VL, nullptr,
            NP, KVD, KVD, KVD, KVD, KVD,
            (long)NP * KVD, 0, 0, (long)KVD * KVD,
            (long)HH * NP * KVD, (long)NP * KVD, HH, 1.0f);

        // Qt stacked: branch i -> rows [roff[i], roff[i]+c) of Qt[z][960][224]
        for (int i = 0; i < 4; i++) {
            int c = Cc[i];
            gemm_split<1,0><<<dim3(2, divup(c, 128), g), blk, 0, stream>>>(
                wqH + wqo[i], wqL + wqo[i],
                eiH + eio[i] + (long)b0 * NP * c, eiL + eio[i] + (long)b0 * NP * c,
                nullptr, QtH + (long)roff[i] * KP, QtL + (long)roff[i] * KP, nullptr,
                c, NP, c, c, c, KP,
                0, (long)c * c, (long)NP * c, 0,
                (long)HH * SM * KP, (long)SM * KP, HH, 1.0f);
        }

        // S[z][960][960] fp16 = (Qt @ Kt^T)/sqrt(960); 64 stats slots per map
        gemm_split<2,1><<<dim3(8, 8, g), blk, 0, stream>>>(
            QtH, QtL, KtH, KtL,
            nullptr, Sb, nullptr, part,
            SM, KVD, KP, KP, LDK, KVD,
            (long)SM * KP, 0, (long)KVD * LDK, 0, (long)SM * KVD, 0,
            1, alphaS);

        // fused per-branch instance-norm softmax + PV -> stacked Cb fp16
        pv_fused<<<dim3(1, SM / 64, g), blk, 0, stream>>>(
            Sb, VH, VL, part, Cb, m0);
    }

    // ---- epilogue per branch: head-mean+transpose, then out-projection ----
    for (int i = 0; i < 4; i++) {
        int c = Cc[i];
        mean_t_kernel<<<dim3(divup(NP, 32), c / 32, BB), blk, 0, stream>>>(
            Cb, MbH, MbL, c, roff[i]);
        gemm_split<0,0><<<dim3(divup(c, 128), divup(BB * NP, 128), 1), blk, 0, stream>>>(
            MbH, MbL, woH + woo[i], woL + woo[i],
            out + obase[i], nullptr, nullptr, nullptr,
            BB * NP, c, c, c, c, c,
            0, 0, 0, 0, 0, 0, 1, 1.0f);
    }
}